// Round 8
// baseline (218.989 us; speedup 1.0000x reference)
//
#include <hip/hip_runtime.h>
#include <hip/hip_bf16.h>

#define N_NODES 16384
#define E_EDGES 131072
#define F_IN 6
#define S_DIM 4
#define G_GRAPHS 256
#define H_DIM 30
#define C1 32
#define C2 64
#define C3 32

typedef __attribute__((ext_vector_type(8))) short bf16x8;
typedef __attribute__((ext_vector_type(4))) float f32x4;

__device__ __forceinline__ short f2bf(float f) {
    union { float f; unsigned u; } a; a.f = f;
    unsigned r = a.u + 0x7FFFu + ((a.u >> 16) & 1u);
    return (short)(r >> 16);
}

// pack two f32 -> (bf16(a) low16, bf16(b) high16)
__device__ __forceinline__ unsigned pack2(float a, float b) {
    unsigned ua = __float_as_uint(a) + 0x8000u;
    unsigned ub = __float_as_uint(b) + 0x8000u;
    return __builtin_amdgcn_perm(ub, ua, 0x07060302u);
}

// ---------------------------------------------------------------------------
// prep: build wbt1/wbt2 + degree histogram (deg pre-zeroed by memset).
// ---------------------------------------------------------------------------
__global__ __launch_bounds__(256) void prep(
    const float* __restrict__ wk2, const float* __restrict__ bk2,
    const float* __restrict__ wk1, const float* __restrict__ bk1,
    const int* __restrict__ tgt,
    short* __restrict__ wbt2, short* __restrict__ wbt1,
    int* __restrict__ deg)
{
    const int gtid = blockIdx.x * 256 + threadIdx.x;
    if (gtid < 65536) {
        const int idx = gtid;
        const int j = idx & 7, kq = (idx >> 3) & 3, n = (idx >> 5) & 15;
        const int nt = (idx >> 9) & 3, kc = idx >> 11;
        const int c1 = kq * 8 + j, c2 = nt * 16 + n;
        float v = (kc < 30) ? wk2[kc * 2048 + c1 * 64 + c2]
                            : ((kc == 30) ? bk2[c1 * 64 + c2] : 0.f);
        wbt2[idx] = f2bf(v);
    } else if (gtid < 73728) {
        const int i2 = gtid - 65536;
        const int j = i2 & 7, kq = (i2 >> 3) & 3, n = (i2 >> 5) & 15;
        const int nt = (i2 >> 9) & 1, kc = i2 >> 10;
        const int h = kc * 4 + kq, c1 = nt * 16 + n;
        float v = 0.f;
        if (j < 6) {
            if (h < 30) v = wk1[h * 192 + j * 32 + c1];
            else if (h == 30) v = bk1[j * 32 + c1];
        }
        wbt1[i2] = f2bf(v);
    }
    atomicAdd(&deg[tgt[gtid]], 1);
}

// single block, 1024 threads, 16 elems/thread exclusive scan over N=16384
__global__ __launch_bounds__(1024) void csr_scan(
    const int* __restrict__ deg, int* __restrict__ off, int* __restrict__ cursor)
{
    __shared__ int s[1024];
    const int t = threadIdx.x;
    const int base = t * 16;
    int loc[16]; int sum = 0;
    #pragma unroll
    for (int i = 0; i < 16; ++i) { loc[i] = sum; sum += deg[base + i]; }
    s[t] = sum;
    __syncthreads();
    int v = sum;
    for (int d = 1; d < 1024; d <<= 1) {
        const int add = (t >= d) ? s[t - d] : 0;
        __syncthreads();
        v += add; s[t] = v;
        __syncthreads();
    }
    const int pre = v - sum;
    #pragma unroll
    for (int i = 0; i < 16; ++i) {
        const int o = pre + loc[i];
        off[base + i] = o; cursor[base + i] = o;
    }
    if (t == 1023) off[N_NODES] = E_EDGES;
}

// ---------------------------------------------------------------------------
// ECC1 + fused CSR permute, 128 edges/block, high occupancy.
// Phase A: thread pair per edge (each half computes h0 fully, half of h1).
// ---------------------------------------------------------------------------
__global__ __launch_bounds__(256, 4) void ecc1_mfma(
    const float* __restrict__ x, const float* __restrict__ e,
    const int* __restrict__ src, const int* __restrict__ tgt,
    const float* __restrict__ gcn_w,
    const float* __restrict__ w0, const float* __restrict__ b0,
    const float* __restrict__ w1, const float* __restrict__ b1,
    const short* __restrict__ wbt1,
    int* __restrict__ cursor, int* __restrict__ perm,
    int* __restrict__ srcp, float* __restrict__ gwp,
    unsigned* __restrict__ msg1)
{
    __shared__ unsigned short s_h1b[128 * 40];
    __shared__ unsigned short s_xb[128 * 8];
    __shared__ int s_perm[128];
    __shared__ float s_w0[120], s_b0[30], s_w1[900], s_b1[30];

    const int t = threadIdx.x;
    const int tile = blockIdx.x * 128;
    for (int i = t; i < 120; i += 256) s_w0[i] = w0[i];
    for (int i = t; i < 900; i += 256) s_w1[i] = w1[i];
    if (t < 30) { s_b0[t] = b0[t]; s_b1[t] = b1[t]; }
    __syncthreads();

    // ---- phase A ----
    {
        const int el = t & 127, hf = t >> 7;
        const int eid = tile + el;
        if (hf == 0) {
            const int sv = src[eid];
            const int p = atomicAdd(&cursor[tgt[eid]], 1);
            s_perm[el] = p;
            perm[eid] = p;
            srcp[p] = sv;
            gwp[p] = gcn_w[eid];
            const float2* xp = (const float2*)(x + (size_t)sv * F_IN);
            const float2 a = xp[0], b2 = xp[1], c2 = xp[2];
            *(uint4*)&s_xb[el * 8] =
                make_uint4(pack2(a.x, a.y), pack2(b2.x, b2.y), pack2(c2.x, c2.y), 0u);
        }
        const float4 ev = *(const float4*)(e + eid * 4);
        float h0[30];
        #pragma unroll
        for (int j = 0; j < 30; ++j) {
            float v = ev.x * s_w0[j] + ev.y * s_w0[30 + j]
                    + ev.z * s_w0[60 + j] + ev.w * s_w0[90 + j] + s_b0[j];
            h0[j] = fmaxf(v, 0.f);
        }
        const int i0 = hf ? 8 : 0, i1 = hf ? 15 : 8;
        unsigned hw[8];
        for (int i = i0; i < i1; ++i) {
            float va = s_b1[2 * i], vb = s_b1[2 * i + 1];
            #pragma unroll
            for (int k = 0; k < 30; ++k) {
                va += h0[k] * s_w1[k * 30 + 2 * i];
                vb += h0[k] * s_w1[k * 30 + 2 * i + 1];
            }
            hw[i - i0] = pack2(fmaxf(va, 0.f), fmaxf(vb, 0.f));
        }
        uint4* hb = (uint4*)&s_h1b[el * 40];
        if (hf == 0) {
            hb[0] = make_uint4(hw[0], hw[1], hw[2], hw[3]);
            hb[1] = make_uint4(hw[4], hw[5], hw[6], hw[7]);
        } else {
            hb[2] = make_uint4(hw[0], hw[1], hw[2], hw[3]);
            hb[3] = make_uint4(hw[4], hw[5], hw[6], pack2(1.0f, 0.f));
        }
    }
    __syncthreads();

    // ---- MFMA: 4 waves x 2 m-tiles ----
    const int wv = t >> 6, lane = t & 63;
    const int n = lane & 15, quad = lane >> 4;
    const int e0 = wv * 32;

    float xf[2][8];
    #pragma unroll
    for (int m = 0; m < 2; ++m) {
        const uint4 xv = *(const uint4*)&s_xb[(e0 + m * 16 + n) * 8];
        xf[m][0] = __uint_as_float(xv.x << 16);
        xf[m][1] = __uint_as_float(xv.x & 0xFFFF0000u);
        xf[m][2] = __uint_as_float(xv.y << 16);
        xf[m][3] = __uint_as_float(xv.y & 0xFFFF0000u);
        xf[m][4] = __uint_as_float(xv.z << 16);
        xf[m][5] = __uint_as_float(xv.z & 0xFFFF0000u);
        xf[m][6] = 0.f; xf[m][7] = 0.f;
    }

    f32x4 acc[2][2];
    #pragma unroll
    for (int m = 0; m < 2; ++m) {
        acc[m][0] = (f32x4){0.f, 0.f, 0.f, 0.f};
        acc[m][1] = (f32x4){0.f, 0.f, 0.f, 0.f};
    }

    #pragma unroll
    for (int kc = 0; kc < 8; ++kc) {
        bf16x8 bfr[2];
        #pragma unroll
        for (int nt = 0; nt < 2; ++nt)
            bfr[nt] = *(const bf16x8*)(wbt1 + (((kc * 2 + nt) * 16 + n) << 5) + quad * 8);
        #pragma unroll
        for (int m = 0; m < 2; ++m) {
            const unsigned hv = s_h1b[(e0 + m * 16 + n) * 40 + kc * 4 + quad];
            const float hfv = __uint_as_float(hv << 16);
            union { unsigned u[4]; bf16x8 v; } af;
            #pragma unroll
            for (int i = 0; i < 4; ++i)
                af.u[i] = pack2(hfv * xf[m][2 * i], hfv * xf[m][2 * i + 1]);
            acc[m][0] = __builtin_amdgcn_mfma_f32_16x16x32_bf16(af.v, bfr[0], acc[m][0], 0, 0, 0);
            acc[m][1] = __builtin_amdgcn_mfma_f32_16x16x32_bf16(af.v, bfr[1], acc[m][1], 0, 0, 0);
        }
    }

    #pragma unroll
    for (int m = 0; m < 2; ++m)
        #pragma unroll
        for (int r = 0; r < 4; ++r) {
            const int p = s_perm[e0 + m * 16 + quad * 4 + r];
            msg1[p * 16 + n] = pack2(acc[m][0][r], acc[m][1][r]);
        }
}

// gather msg1 (sequential, permuted layout) + node update 1 -> x1
__global__ __launch_bounds__(256) void gather1(
    const unsigned* __restrict__ msg1, const int* __restrict__ off,
    const float* __restrict__ x,
    const float* __restrict__ root, const float* __restrict__ bias,
    float* __restrict__ x1)
{
    __shared__ float s_root[192];
    __shared__ float s_b[32];
    const int t = threadIdx.x;
    if (t < 192) s_root[t] = root[t];
    if (t < 32) s_b[t] = bias[t];
    __syncthreads();
    const int v = blockIdx.x * 16 + (t >> 4);
    const int n = t & 15;
    const int o0 = off[v], o1 = off[v + 1];
    float sa = 0.f, sb = 0.f;
    for (int j = o0; j < o1; ++j) {
        const unsigned u = msg1[j * 16 + n];
        sa += __uint_as_float(u << 16);
        sb += __uint_as_float(u & 0xFFFF0000u);
    }
    const float* xr = x + (size_t)v * F_IN;
    float ra = s_b[n], rb = s_b[16 + n];
    #pragma unroll
    for (int f = 0; f < 6; ++f) {
        const float xv = xr[f];
        ra += xv * s_root[f * 32 + n];
        rb += xv * s_root[f * 32 + 16 + n];
    }
    x1[v * 32 + n] = fmaxf(sa + ra, 0.f);
    x1[v * 32 + 16 + n] = fmaxf(sb + rb, 0.f);
}

// ---------------------------------------------------------------------------
// ECC2: 128 edges/block, high occupancy, permuted msg stores.
// ---------------------------------------------------------------------------
__global__ __launch_bounds__(256, 4) void ecc2_mfma(
    const float* __restrict__ x1, const float* __restrict__ e,
    const int* __restrict__ src, const int* __restrict__ perm,
    const float* __restrict__ w0, const float* __restrict__ b0,
    const float* __restrict__ w1, const float* __restrict__ b1,
    const short* __restrict__ wbt2, unsigned* __restrict__ msg2)
{
    __shared__ unsigned short s_h1b[128 * 40];
    __shared__ unsigned short s_x1b[128 * 40];
    __shared__ int s_perm[128];
    __shared__ float s_w0[120], s_b0[30], s_w1[900], s_b1[30];

    const int t = threadIdx.x;
    const int tile = blockIdx.x * 128;
    for (int i = t; i < 120; i += 256) s_w0[i] = w0[i];
    for (int i = t; i < 900; i += 256) s_w1[i] = w1[i];
    if (t < 30) { s_b0[t] = b0[t]; s_b1[t] = b1[t]; }
    __syncthreads();

    // ---- phase A ----
    {
        const int el = t & 127, hf = t >> 7;
        const int eid = tile + el;
        if (hf == 0) s_perm[el] = perm[eid];
        // stage x1[src]: each half stages 16 floats
        {
            const float* xp = x1 + (size_t)src[eid] * C1 + hf * 16;
            uint4* xb = (uint4*)&s_x1b[el * 40];
            #pragma unroll
            for (int q = 0; q < 2; ++q) {
                const float4 v0 = *(const float4*)(xp + q * 8);
                const float4 v1 = *(const float4*)(xp + q * 8 + 4);
                xb[hf * 2 + q] = make_uint4(pack2(v0.x, v0.y), pack2(v0.z, v0.w),
                                            pack2(v1.x, v1.y), pack2(v1.z, v1.w));
            }
        }
        const float4 ev = *(const float4*)(e + eid * 4);
        float h0[30];
        #pragma unroll
        for (int j = 0; j < 30; ++j) {
            float v = ev.x * s_w0[j] + ev.y * s_w0[30 + j]
                    + ev.z * s_w0[60 + j] + ev.w * s_w0[90 + j] + s_b0[j];
            h0[j] = fmaxf(v, 0.f);
        }
        const int i0 = hf ? 8 : 0, i1 = hf ? 15 : 8;
        unsigned hw[8];
        for (int i = i0; i < i1; ++i) {
            float va = s_b1[2 * i], vb = s_b1[2 * i + 1];
            #pragma unroll
            for (int k = 0; k < 30; ++k) {
                va += h0[k] * s_w1[k * 30 + 2 * i];
                vb += h0[k] * s_w1[k * 30 + 2 * i + 1];
            }
            hw[i - i0] = pack2(fmaxf(va, 0.f), fmaxf(vb, 0.f));
        }
        uint4* hb = (uint4*)&s_h1b[el * 40];
        if (hf == 0) {
            hb[0] = make_uint4(hw[0], hw[1], hw[2], hw[3]);
            hb[1] = make_uint4(hw[4], hw[5], hw[6], hw[7]);
        } else {
            hb[2] = make_uint4(hw[0], hw[1], hw[2], hw[3]);
            hb[3] = make_uint4(hw[4], hw[5], hw[6], pack2(1.0f, 0.f));
        }
    }
    __syncthreads();

    // ---- MFMA: 4 waves x 2 m-tiles x 4 n-tiles ----
    const int wv = t >> 6, lane = t & 63;
    const int n = lane & 15, quad = lane >> 4;
    const int e0 = wv * 32;

    float xf[2][8];
    #pragma unroll
    for (int m = 0; m < 2; ++m) {
        const uint4 xv = *(const uint4*)&s_x1b[(e0 + m * 16 + n) * 40 + quad * 8];
        xf[m][0] = __uint_as_float(xv.x << 16);
        xf[m][1] = __uint_as_float(xv.x & 0xFFFF0000u);
        xf[m][2] = __uint_as_float(xv.y << 16);
        xf[m][3] = __uint_as_float(xv.y & 0xFFFF0000u);
        xf[m][4] = __uint_as_float(xv.z << 16);
        xf[m][5] = __uint_as_float(xv.z & 0xFFFF0000u);
        xf[m][6] = __uint_as_float(xv.w << 16);
        xf[m][7] = __uint_as_float(xv.w & 0xFFFF0000u);
    }

    f32x4 acc[2][4];
    #pragma unroll
    for (int m = 0; m < 2; ++m)
        #pragma unroll
        for (int nt = 0; nt < 4; ++nt) acc[m][nt] = (f32x4){0.f, 0.f, 0.f, 0.f};

    #pragma unroll 4
    for (int kc = 0; kc < 32; ++kc) {
        bf16x8 bfr[4];
        #pragma unroll
        for (int nt = 0; nt < 4; ++nt)
            bfr[nt] = *(const bf16x8*)(wbt2 + (((kc * 4 + nt) * 16 + n) << 5) + quad * 8);
        #pragma unroll
        for (int m = 0; m < 2; ++m) {
            const unsigned hv = s_h1b[(e0 + m * 16 + n) * 40 + kc];
            const float hfv = __uint_as_float(hv << 16);
            union { unsigned u[4]; bf16x8 v; } af;
            #pragma unroll
            for (int i = 0; i < 4; ++i)
                af.u[i] = pack2(hfv * xf[m][2 * i], hfv * xf[m][2 * i + 1]);
            #pragma unroll
            for (int nt = 0; nt < 4; ++nt)
                acc[m][nt] = __builtin_amdgcn_mfma_f32_16x16x32_bf16(af.v, bfr[nt], acc[m][nt], 0, 0, 0);
        }
    }

    #pragma unroll
    for (int m = 0; m < 2; ++m)
        #pragma unroll
        for (int r = 0; r < 4; ++r) {
            const int p = s_perm[e0 + m * 16 + quad * 4 + r];
            uint2 val;
            val.x = pack2(acc[m][0][r], acc[m][1][r]);
            val.y = pack2(acc[m][2][r], acc[m][3][r]);
            *(uint2*)&msg2[p * 32 + n * 2] = val;
        }
}

// gather msg2 (sequential) + node update 2 + xw = x2 @ gcn_W -> xw
__global__ __launch_bounds__(256) void gather2(
    const unsigned* __restrict__ msg2, const int* __restrict__ off,
    const float* __restrict__ x1,
    const float* __restrict__ root, const float* __restrict__ bias,
    const float* __restrict__ W, float* __restrict__ xw)
{
    __shared__ float s_root[2048], s_W[2048], s_b[64];
    __shared__ float s_x2[8][68];
    __shared__ float s_x1v[256];
    const int t = threadIdx.x;
    for (int i = t; i < 2048; i += 256) { s_root[i] = root[i]; s_W[i] = W[i]; }
    if (t < 64) s_b[t] = bias[t];
    s_x1v[t] = x1[blockIdx.x * 256 + t];
    __syncthreads();

    const int lv = t >> 5;
    const int v = blockIdx.x * 8 + lv;
    const int j5 = t & 31;
    const int n = j5 >> 1, p = j5 & 1;
    const int ca = p * 32 + n, cb = p * 32 + 16 + n;
    const int o0 = off[v], o1 = off[v + 1];
    float sa = 0.f, sb = 0.f;
    for (int j = o0; j < o1; ++j) {
        const unsigned u = msg2[j * 32 + j5];
        sa += __uint_as_float(u << 16);
        sb += __uint_as_float(u & 0xFFFF0000u);
    }
    float ra = s_b[ca], rb = s_b[cb];
    #pragma unroll 8
    for (int k = 0; k < 32; ++k) {
        const float xv = s_x1v[lv * 32 + k];
        ra += xv * s_root[k * 64 + ca];
        rb += xv * s_root[k * 64 + cb];
    }
    s_x2[lv][ca] = fmaxf(sa + ra, 0.f);
    s_x2[lv][cb] = fmaxf(sb + rb, 0.f);
    __syncthreads();

    float av = 0.f;
    #pragma unroll 8
    for (int k = 0; k < 64; ++k) av += s_x2[lv][k] * s_W[k * 32 + j5];
    xw[v * 32 + j5] = av;
}

// GCN gather (CSR-ordered srcp/gwp, sequential) + relu + global pool
__global__ __launch_bounds__(256) void gcn_pool(
    const float* __restrict__ xw, const int* __restrict__ off,
    const int* __restrict__ srcp, const float* __restrict__ gwp,
    const float* __restrict__ gw, const float* __restrict__ gb,
    const int* __restrict__ seg, float* __restrict__ out)
{
    __shared__ float s_gb[32];
    const int t = threadIdx.x;
    if (t < 32) s_gb[t] = gb[t];
    __syncthreads();
    const int v = blockIdx.x * 8 + (t >> 5);
    const int c = t & 31;
    const int o0 = off[v], o1 = off[v + 1];
    float s = gw[E_EDGES + v] * xw[v * 32 + c];   // self loop
    for (int j = o0; j < o1; ++j)
        s += gwp[j] * xw[srcp[j] * 32 + c];
    const float val = fmaxf(s + s_gb[c], 0.f);
    atomicAdd(&out[seg[v] * 32 + c], val);
}

extern "C" void kernel_launch(void* const* d_in, const int* in_sizes, int n_in,
                              void* d_out, int out_size, void* d_ws, size_t ws_size,
                              hipStream_t stream)
{
    const float* x       = (const float*)d_in[0];
    const float* e       = (const float*)d_in[1];
    const int*   src     = (const int*)d_in[2];
    const int*   tgt     = (const int*)d_in[3];
    const int*   seg     = (const int*)d_in[4];
    const float* gcn_w   = (const float*)d_in[7];
    const float* e1_w0   = (const float*)d_in[8];
    const float* e1_b0   = (const float*)d_in[9];
    const float* e1_w1   = (const float*)d_in[10];
    const float* e1_b1   = (const float*)d_in[11];
    const float* e1_wk   = (const float*)d_in[12];
    const float* e1_bk   = (const float*)d_in[13];
    const float* e1_root = (const float*)d_in[14];
    const float* e1_bias = (const float*)d_in[15];
    const float* e2_w0   = (const float*)d_in[16];
    const float* e2_b0   = (const float*)d_in[17];
    const float* e2_w1   = (const float*)d_in[18];
    const float* e2_b1   = (const float*)d_in[19];
    const float* e2_wk   = (const float*)d_in[20];
    const float* e2_bk   = (const float*)d_in[21];
    const float* e2_root = (const float*)d_in[22];
    const float* e2_bias = (const float*)d_in[23];
    const float* gcn_W   = (const float*)d_in[24];
    const float* gcn_b   = (const float*)d_in[25];
    float* out = (float*)d_out;

    float*    ws    = (float*)d_ws;
    float*    x1    = ws;                                   // [N,32]
    float*    xw    = x1 + (size_t)N_NODES * 32;            // [N,32]
    unsigned* msg1  = (unsigned*)(xw + (size_t)N_NODES * 32);   // E*16 u32
    unsigned* msg2  = msg1 + (size_t)E_EDGES * 16;          // E*32 u32
    short*    wbt2  = (short*)(msg2 + (size_t)E_EDGES * 32);// 65536 bf16
    short*    wbt1  = wbt2 + 65536;                         // 8192 bf16
    int*      deg   = (int*)(wbt1 + 8192);                  // N
    int*      off   = deg + N_NODES;                        // N+1 (+pad)
    int*      cursor= off + N_NODES + 16;                   // N
    int*      perm  = cursor + N_NODES;                     // E
    int*      srcp  = perm + E_EDGES;                       // E
    float*    gwp   = (float*)(srcp + E_EDGES);             // E

    hipMemsetAsync(deg, 0, N_NODES * sizeof(int), stream);
    hipMemsetAsync(out, 0, (size_t)out_size * sizeof(float), stream);

    prep<<<E_EDGES / 256, 256, 0, stream>>>(e2_wk, e2_bk, e1_wk, e1_bk, tgt,
        wbt2, wbt1, deg);
    csr_scan<<<1, 1024, 0, stream>>>(deg, off, cursor);

    ecc1_mfma<<<E_EDGES / 128, 256, 0, stream>>>(x, e, src, tgt, gcn_w,
        e1_w0, e1_b0, e1_w1, e1_b1, wbt1, cursor, perm, srcp, gwp, msg1);
    gather1<<<N_NODES / 16, 256, 0, stream>>>(msg1, off, x, e1_root, e1_bias, x1);
    ecc2_mfma<<<E_EDGES / 128, 256, 0, stream>>>(x1, e, src, perm,
        e2_w0, e2_b0, e2_w1, e2_b1, wbt2, msg2);
    gather2<<<N_NODES / 8, 256, 0, stream>>>(msg2, off, x1,
        e2_root, e2_bias, gcn_W, xw);
    gcn_pool<<<N_NODES / 8, 256, 0, stream>>>(xw, off, srcp, gwp,
        gcn_w, gcn_b, seg, out);
}